// Round 1
// baseline (71.854 us; speedup 1.0000x reference)
//
#include <hip/hip_runtime.h>

// Problem: x [E=512][N=65536] fp32.
//   sum_abs[col] = sum_{e=1..E-1} |x[e][col]|
//   lb = x0 - sum_abs; ub = x0 + sum_abs
//   crossing = lb<=0 && ub>=0 ; dead = ub<=0
//   alpha = crossing ? 1-lb : 1
//   out[0]   = dead?0 : crossing? alpha*x0 - alpha*lb*0.5 : x0
//   out[e>0] = dead?0 : crossing? alpha*x : x
// Memory-bound: 2 reads + 1 write of 128 MiB.

#define EROWS 512
#define ROW_CHUNKS 8

__global__ void ar_reduce(const float* __restrict__ x, float* __restrict__ part, int n4) {
    int col4 = blockIdx.x * blockDim.x + threadIdx.x;  // float4 column index
    if (col4 >= n4) return;
    const int rowsPer = EROWS / ROW_CHUNKS;            // 64
    int r0 = blockIdx.y * rowsPer;
    int r1 = r0 + rowsPer;
    int r  = (r0 == 0) ? 1 : r0;                       // exclude center row
    const float4* xv = (const float4*)x;
    float4 acc = {0.f, 0.f, 0.f, 0.f};
    for (; r < r1; ++r) {
        float4 v = xv[(size_t)r * n4 + col4];
        acc.x += fabsf(v.x);
        acc.y += fabsf(v.y);
        acc.z += fabsf(v.z);
        acc.w += fabsf(v.w);
    }
    ((float4*)part)[(size_t)blockIdx.y * n4 + col4] = acc;
}

__global__ void ar_finalize(const float* __restrict__ x, const float* __restrict__ part,
                            float* __restrict__ scale, float* __restrict__ out, int n4) {
    int col4 = blockIdx.x * blockDim.x + threadIdx.x;
    if (col4 >= n4) return;
    const float4* pv = (const float4*)part;
    float s[4] = {0.f, 0.f, 0.f, 0.f};
    for (int c = 0; c < ROW_CHUNKS; ++c) {
        float4 p = pv[(size_t)c * n4 + col4];
        s[0] += p.x; s[1] += p.y; s[2] += p.z; s[3] += p.w;
    }
    float4 x0v = ((const float4*)x)[col4];
    float x0[4] = {x0v.x, x0v.y, x0v.z, x0v.w};
    float sc[4], o0[4];
    #pragma unroll
    for (int j = 0; j < 4; ++j) {
        float lb = x0[j] - s[j];
        float ub = x0[j] + s[j];
        bool crossing = (lb <= 0.f) && (ub >= 0.f);
        bool dead = (ub <= 0.f);
        float alpha = crossing ? (1.f - lb) : 1.f;
        float scl = dead ? 0.f : (crossing ? alpha : 1.f);
        float addv = (crossing && !dead) ? (-alpha * lb * 0.5f) : 0.f;
        sc[j] = scl;
        o0[j] = scl * x0[j] + addv;
    }
    float4 scv = {sc[0], sc[1], sc[2], sc[3]};
    float4 o0v = {o0[0], o0[1], o0[2], o0[3]};
    ((float4*)scale)[col4] = scv;
    ((float4*)out)[col4] = o0v;   // row 0
}

__global__ void ar_apply(const float* __restrict__ x, const float* __restrict__ scale,
                         float* __restrict__ out, int n4, int total4) {
    size_t stride = (size_t)gridDim.x * blockDim.x;
    const float4* xv = (const float4*)x;
    const float4* sv = (const float4*)scale;
    float4* ov = (float4*)out;
    int mask = n4 - 1;  // n4 is a power of two (16384)
    for (size_t i = (size_t)blockIdx.x * blockDim.x + threadIdx.x + (size_t)n4;
         i < (size_t)total4; i += stride) {
        int col4 = (int)(i & (size_t)mask);
        float4 v = xv[i];
        float4 s = sv[col4];
        float4 o;
        o.x = v.x * s.x;
        o.y = v.y * s.y;
        o.z = v.z * s.z;
        o.w = v.w * s.w;
        ov[i] = o;
    }
}

extern "C" void kernel_launch(void* const* d_in, const int* in_sizes, int n_in,
                              void* d_out, int out_size, void* d_ws, size_t ws_size,
                              hipStream_t stream) {
    const float* x = (const float*)d_in[0];
    float* out = (float*)d_out;
    int total = in_sizes[0];          // 512 * 65536
    int N = total / EROWS;            // 65536
    int n4 = N >> 2;                  // 16384
    int total4 = total >> 2;

    float* part  = (float*)d_ws;                       // ROW_CHUNKS * N floats
    float* scale = part + (size_t)ROW_CHUNKS * N;      // N floats

    dim3 gridA(n4 / 256, ROW_CHUNKS);
    ar_reduce<<<gridA, 256, 0, stream>>>(x, part, n4);
    ar_finalize<<<n4 / 256, 256, 0, stream>>>(x, part, scale, out, n4);
    ar_apply<<<2048, 256, 0, stream>>>(x, scale, out, n4, total4);
}

// Round 2
// 45.718 us; speedup vs baseline: 1.5717x; 1.5717x over previous
//
#include <hip/hip_runtime.h>

// x [E=512][N=65536] fp32.
//   sum_abs[col] = sum_{e>=1} |x[e][col]|
//   lb = x0 - sum_abs; ub = x0 + sum_abs
//   crossing = lb<=0 && ub>=0 ; dead = ub<=0
//   alpha = crossing ? 1-lb : 1
//   out[0]   = dead?0 : crossing? alpha*x0 - alpha*lb*0.5 : x0
//   out[e>0] = dead?0 : crossing? alpha*x : x
//
// Single-pass: each block owns a 32-column slab, reads all 512 rows ONCE
// (staging in LDS + accumulating |x| in registers), computes scale, rescales
// from LDS. HBM traffic = 134 MB read + 134 MB write (min possible).

#define EROWS 512
#define W4 8                      // float4 column-groups per block (32 cols)
#define BLK 256
#define ROWS_PER_ITER (BLK / W4)  // 32 rows loaded per iteration
#define NITER (EROWS / ROWS_PER_ITER)  // 16

__global__ __launch_bounds__(BLK) void ar_fused(const float* __restrict__ x,
                                                float* __restrict__ out, int n4) {
    __shared__ float4 slab[EROWS * W4];  // 64 KiB: [row][cseg]
    __shared__ float4 part[BLK];         // 4 KiB per-thread partial |x| sums
    __shared__ float4 scale4[W4];

    int t = threadIdx.x;
    int cseg  = t & (W4 - 1);   // 0..7  — this thread's fixed float4 col group
    int rbase = t >> 3;         // 0..31 — starting row
    int col4_0 = blockIdx.x * W4;

    const float4* xv = (const float4*)x;
    float4* ov = (float4*)out;

    // ---- single global read: stage to LDS + accumulate |x| (row 0 excluded)
    float4 acc = {0.f, 0.f, 0.f, 0.f};
    {
        // k = 0 peeled (row 0 exclusion is only possible here, rbase==0)
        float4 v = xv[(size_t)rbase * n4 + col4_0 + cseg];
        slab[rbase * W4 + cseg] = v;
        if (rbase != 0) {
            acc.x += fabsf(v.x); acc.y += fabsf(v.y);
            acc.z += fabsf(v.z); acc.w += fabsf(v.w);
        }
    }
    #pragma unroll
    for (int k = 1; k < NITER; ++k) {
        int row = rbase + k * ROWS_PER_ITER;
        float4 v = xv[(size_t)row * n4 + col4_0 + cseg];
        slab[row * W4 + cseg] = v;
        acc.x += fabsf(v.x); acc.y += fabsf(v.y);
        acc.z += fabsf(v.z); acc.w += fabsf(v.w);
    }
    part[t] = acc;
    __syncthreads();

    // ---- finalize: 8 threads, one per float4 col group
    if (t < W4) {
        float4 s = {0.f, 0.f, 0.f, 0.f};
        for (int j = 0; j < ROWS_PER_ITER; ++j) {
            float4 p = part[j * W4 + t];
            s.x += p.x; s.y += p.y; s.z += p.z; s.w += p.w;
        }
        float4 x0v = slab[t];  // row 0, col group t
        float x0[4] = {x0v.x, x0v.y, x0v.z, x0v.w};
        float sm[4] = {s.x, s.y, s.z, s.w};
        float sc[4], o0[4];
        #pragma unroll
        for (int j = 0; j < 4; ++j) {
            float lb = x0[j] - sm[j];
            float ub = x0[j] + sm[j];
            bool crossing = (lb <= 0.f) && (ub >= 0.f);
            bool dead = (ub <= 0.f);
            float alpha = crossing ? (1.f - lb) : 1.f;
            float scl = dead ? 0.f : (crossing ? alpha : 1.f);
            float addv = (crossing && !dead) ? (-alpha * lb * 0.5f) : 0.f;
            sc[j] = scl;
            o0[j] = scl * x0[j] + addv;
        }
        float4 scv = {sc[0], sc[1], sc[2], sc[3]};
        float4 o0v = {o0[0], o0[1], o0[2], o0[3]};
        scale4[t] = scv;
        ov[col4_0 + t] = o0v;  // row 0 output
    }
    __syncthreads();

    // ---- rescale rows 1..511 from LDS, write out
    for (int i = W4 + t; i < EROWS * W4; i += BLK) {
        int row = i >> 3;       // i / W4
        int cs  = i & (W4 - 1);
        float4 v = slab[i];
        float4 s = scale4[cs];
        float4 o;
        o.x = v.x * s.x; o.y = v.y * s.y;
        o.z = v.z * s.z; o.w = v.w * s.w;
        ov[(size_t)row * n4 + col4_0 + cs] = o;
    }
}

extern "C" void kernel_launch(void* const* d_in, const int* in_sizes, int n_in,
                              void* d_out, int out_size, void* d_ws, size_t ws_size,
                              hipStream_t stream) {
    const float* x = (const float*)d_in[0];
    float* out = (float*)d_out;
    int total = in_sizes[0];     // 512 * 65536
    int N = total / EROWS;       // 65536
    int n4 = N >> 2;             // 16384 float4 per row
    int nblocks = n4 / W4;       // 2048

    ar_fused<<<nblocks, BLK, 0, stream>>>(x, out, n4);
}